// Round 2
// baseline (375.502 us; speedup 1.0000x reference)
//
#include <hip/hip_runtime.h>

// Problem constants (b=8, H=W=56, cin=64, cout=64, cmid=32, k=3, G=4, gc=16)
// ALL inputs and the output are float32 (per reference setup_inputs).
// Internal GEMM runs in bf16 (2% rel threshold permits it).
#define BATCH 8
#define PIX   3136          // 56*56
#define CIN8  512           // cin*8
#define CMID8 256
#define KDIM  512

typedef short short8 __attribute__((ext_vector_type(8)));
typedef float f32x4 __attribute__((ext_vector_type(4)));

__constant__ int c_perms[8][8] = {
    {0, 1, 2, 3, 4, 5, 6, 7},
    {3, 0, 1, 2, 5, 6, 7, 4},
    {2, 3, 0, 1, 6, 7, 4, 5},
    {1, 2, 3, 0, 7, 4, 5, 6},
    {4, 5, 6, 7, 0, 1, 2, 3},
    {5, 6, 7, 4, 3, 0, 1, 2},
    {6, 7, 4, 5, 2, 3, 0, 1},
};
__constant__ int c_perm7[8] = {7, 4, 5, 6, 1, 2, 3, 0}; // row 7 (kept table compact)

// TAB[g][p]: source tap (ki'*3+kj') in wgt for output tap p=ki*3+kj.
// g0:(ki,kj) g1:(kj,2-ki) g2:(2-ki,2-kj) g3:(2-kj,ki)
// g4:(ki,2-kj) g5:(2-kj,2-ki) g6:(2-ki,kj) g7:(kj,ki)   [hand-checked vs rot90 algebra]
__constant__ int c_tab[8][9] = {
    {0, 1, 2, 3, 4, 5, 6, 7, 8},
    {2, 5, 8, 1, 4, 7, 0, 3, 6},
    {8, 7, 6, 5, 4, 3, 2, 1, 0},
    {6, 3, 0, 7, 4, 1, 8, 5, 2},
    {2, 1, 0, 5, 4, 3, 8, 7, 6},
    {8, 5, 2, 7, 4, 1, 6, 3, 0},
    {6, 7, 8, 3, 4, 5, 0, 1, 2},
    {0, 3, 6, 1, 4, 7, 2, 5, 8},
};

__device__ __forceinline__ float bf2f(unsigned short u) {
    union { unsigned int i; float f; } v;
    v.i = ((unsigned int)u) << 16;
    return v.f;
}
__device__ __forceinline__ unsigned short f2bf(float f) {
    union { float f; unsigned int u; } v;
    v.f = f;
    unsigned int u = v.u;
    u += 0x7FFFu + ((u >> 16) & 1u);   // RNE
    return (unsigned short)(u >> 16);
}

// ---------------------------------------------------------------------------
// K0a: convert x f32 -> bf16, same [8][512][3136] layout. 4 elems/thread.
// ---------------------------------------------------------------------------
__global__ __launch_bounds__(256) void cvt_x_kernel(
    const float* __restrict__ x, unsigned short* __restrict__ xbf)
{
    int i = (blockIdx.x * 256 + threadIdx.x) * 4;   // 12,845,056 exact
    float4 v = *(const float4*)(x + i);
    ushort2 lo = {f2bf(v.x), f2bf(v.y)};
    ushort2 hi = {f2bf(v.z), f2bf(v.w)};
    *(ushort2*)(xbf + i)     = lo;
    *(ushort2*)(xbf + i + 2) = hi;
}

// ---------------------------------------------------------------------------
// K0b: build 768x512 permuted weight matrix in bf16, k-contiguous.
// rows [0,512): Wbig[o*8+g][i*8+f] = w_v[o][i][PERMS[g][f]]
// rows [512,768): same from w1.
// ---------------------------------------------------------------------------
__global__ __launch_bounds__(256) void build_w_kernel(
    const float* __restrict__ w_v, const float* __restrict__ w1,
    unsigned short* __restrict__ Wbig)
{
    int idx = blockIdx.x * 256 + threadIdx.x;     // 768*512 = 393216 exact
    int r = idx >> 9;
    int k = idx & 511;
    int i = k >> 3, f = k & 7;
    float v;
    if (r < 512) {
        int o = r >> 3, g = r & 7;
        int pf = (g < 7) ? c_perms[g][f] : c_perm7[f];
        v = w_v[(o * 64 + i) * 8 + pf];
    } else {
        int rr = r - 512;
        int o = rr >> 3, g = rr & 7;
        int pf = (g < 7) ? c_perms[g][f] : c_perm7[f];
        v = w1[(o * 64 + i) * 8 + pf];
    }
    Wbig[idx] = f2bf(v);
}

// ---------------------------------------------------------------------------
// K1: MFMA GEMM.  D[row][pixel] = sum_k Wbig[row][k] * xbf[b][k][pixel]
// Tile 64x64, BK=32; 4 waves, each M=64 x N=16 (4 acc tiles of 4 f32/lane).
// rows < 512 -> xv (bf16 out); rows >= 512 -> y1 (f32 out).
// ---------------------------------------------------------------------------
#define LDK 40   // padded LDS row stride (ushorts): 80B -> 2-way (free) b128 conflicts

__global__ __launch_bounds__(256) void gemm_kernel(
    const unsigned short* __restrict__ x,     // xbf [8][512][3136]
    const unsigned short* __restrict__ Wbig,  // [768][512]
    unsigned short* __restrict__ xv,          // [8][512][3136] bf16
    float* __restrict__ y1)                   // [8][256][3136] f32
{
    __shared__ unsigned short Wt[64 * LDK];
    __shared__ unsigned short Xt[64 * LDK];

    const int tid  = threadIdx.x;
    const int lane = tid & 63;
    const int wave = tid >> 6;

    const int flat = blockIdx.x;       // pt*12 + rt (rt fast: row tiles share x tile)
    const int pt   = flat / 12;
    const int rt   = flat % 12;
    const int b    = pt / 49;
    const int p0   = (pt % 49) * 64;
    const int row0 = rt * 64;

    const unsigned short* xb = x + (size_t)b * CIN8 * PIX + p0;

    f32x4 acc[4];
#pragma unroll
    for (int i = 0; i < 4; ++i) acc[i] = (f32x4){0.f, 0.f, 0.f, 0.f};

    const int wm  = tid >> 2;            // W row 0..63
    const int wko = (tid & 3) * 8;       // W k-offset {0,8,16,24}
    const int xk  = tid >> 3;            // x channel-in-chunk 0..31
    const int xn0 = (tid & 7) * 8;       // pixel offset {0..56 step 8}

    const int m16 = lane & 15;
    const int q8  = (lane >> 4) * 8;

    for (int kc = 0; kc < 16; ++kc) {
        const int k0 = kc * 32;
        { // stage W tile (64x32), 16B/thread, k-contiguous
            const unsigned short* src = Wbig + (size_t)(row0 + wm) * KDIM + (k0 + wko);
            *(uint4*)&Wt[wm * LDK + wko] = *(const uint4*)src;
        }
        { // stage X tile transposed: Xt[n][k]
            const unsigned short* src = xb + (size_t)(k0 + xk) * PIX + xn0;
            uint4 v = *(const uint4*)src;
            const unsigned short* vs = (const unsigned short*)&v;
#pragma unroll
            for (int j = 0; j < 8; ++j)
                Xt[(xn0 + j) * LDK + xk] = vs[j];
        }
        __syncthreads();
        short8 bfrag = *(const short8*)&Xt[(wave * 16 + m16) * LDK + q8];
#pragma unroll
        for (int mt = 0; mt < 4; ++mt) {
            short8 afrag = *(const short8*)&Wt[(mt * 16 + m16) * LDK + q8];
            acc[mt] = __builtin_amdgcn_mfma_f32_16x16x32_bf16(afrag, bfrag, acc[mt], 0, 0, 0);
        }
        __syncthreads();
    }

    // epilogue: C/D layout col(n)=lane&15, row(m)=(lane>>4)*4+reg  [m89/m91]
    const int n  = p0 + wave * 16 + m16;
    const int qm = (lane >> 4) * 4;
    if (row0 < 512) {
#pragma unroll
        for (int mt = 0; mt < 4; ++mt) {
            int m = row0 + mt * 16 + qm;
            size_t base = ((size_t)b * CIN8 + m) * PIX + n;
#pragma unroll
            for (int r = 0; r < 4; ++r)
                xv[base + (size_t)r * PIX] = f2bf(acc[mt][r]);
        }
    } else {
#pragma unroll
        for (int mt = 0; mt < 4; ++mt) {
            int m = (row0 - 512) + mt * 16 + qm;
            size_t base = ((size_t)b * CMID8 + m) * PIX + n;
#pragma unroll
            for (int r = 0; r < 4; ++r)
                y1[base + (size_t)r * PIX] = acc[mt][r];
        }
    }
}

// ---------------------------------------------------------------------------
// K2: GroupNorm stats. Group (b,o): 8*3136 = 25088 CONTIGUOUS floats of y1.
// ---------------------------------------------------------------------------
__global__ __launch_bounds__(256) void gn_stats_kernel(
    const float* __restrict__ y1, float* __restrict__ stats)
{
    const float* base = y1 + (size_t)blockIdx.x * 25088;
    float s = 0.f, ss = 0.f;
    for (int i = threadIdx.x; i < 25088; i += 256) {  // 98 iters exact
        float v = base[i];
        s += v; ss += v * v;
    }
#pragma unroll
    for (int off = 32; off; off >>= 1) {
        s  += __shfl_down(s, off);
        ss += __shfl_down(ss, off);
    }
    __shared__ float red[8];
    int wave = threadIdx.x >> 6, lane = threadIdx.x & 63;
    if (lane == 0) { red[wave * 2] = s; red[wave * 2 + 1] = ss; }
    __syncthreads();
    if (threadIdx.x == 0) {
        float S  = red[0] + red[2] + red[4] + red[6];
        float SS = red[1] + red[3] + red[5] + red[7];
        float mean = S * (1.f / 25088.f);
        float var  = SS * (1.f / 25088.f) - mean * mean;
        stats[blockIdx.x * 2]     = mean;
        stats[blockIdx.x * 2 + 1] = rsqrtf(var + 1e-5f);
    }
}

// ---------------------------------------------------------------------------
// K3: normalize + ReLU + 36x32 matmul -> wgt[b][g][o2][p] (f32). thread=(b,g,p)
// ---------------------------------------------------------------------------
__global__ __launch_bounds__(256) void wgt_kernel(
    const float* __restrict__ y1, const float* __restrict__ stats,
    const float* __restrict__ gamma, const float* __restrict__ beta,
    const float* __restrict__ w2, const float* __restrict__ b2,
    float* __restrict__ wgt)
{
    __shared__ float w2s[36 * 32];
    __shared__ float b2s[36];
    for (int i = threadIdx.x; i < 36 * 32; i += 256) w2s[i] = w2[i];
    if (threadIdx.x < 36) b2s[threadIdx.x] = b2[threadIdx.x];
    __syncthreads();

    int idx = blockIdx.x * 256 + threadIdx.x;  // 784 blocks: 8*8*3136 exact
    int p  = idx % PIX;
    int bg = idx / PIX;
    int b = bg >> 3, g = bg & 7;

    float t[32];
#pragma unroll
    for (int i = 0; i < 32; ++i) {
        float mean = stats[(b * 32 + i) * 2];
        float rstd = stats[(b * 32 + i) * 2 + 1];
        float ga = gamma[i * 8 + g];
        float be = beta[i * 8 + g];
        float v = y1[((size_t)(b * CMID8 + i * 8 + g)) * PIX + p];
        v = (v - mean) * rstd * ga + be;
        t[i] = v > 0.f ? v : 0.f;
    }
    size_t ob = (size_t)bg * 36 * PIX + p;
    for (int o2 = 0; o2 < 36; ++o2) {
        float a = b2s[o2];
#pragma unroll
        for (int i = 0; i < 32; ++i) a += w2s[o2 * 32 + i] * t[i];
        wgt[ob + (size_t)o2 * PIX] = a;
    }
}

// ---------------------------------------------------------------------------
// K4: 9-tap symmetrized multiply-sum; out f32.
// out[b][(gidx*16+cc)*8+g][h][w] =
//   sum_p wgt[b][g][gidx*9+TAB[g][p]][h][w] * xv[b][ch][h+ki-1][w+kj-1]
// ---------------------------------------------------------------------------
__global__ __launch_bounds__(256) void final_kernel(
    const float* __restrict__ wgt, const unsigned short* __restrict__ xv,
    float* __restrict__ out)
{
    int idx = blockIdx.x * 256 + threadIdx.x;  // 50176 blocks exact
    int p  = idx % PIX;
    int cb = idx / PIX;
    int ch = cb & 511;
    int b  = cb >> 9;
    int h = p / 56, w = p % 56;
    int g = ch & 7, gidx = ch >> 7;

    const float* wb = wgt + ((size_t)((b * 8 + g) * 36 + gidx * 9)) * PIX + p;
    const unsigned short* xvb = xv + (size_t)cb * PIX;

    float acc = 0.f;
#pragma unroll
    for (int ki = 0; ki < 3; ++ki) {
        int hh = h + ki - 1;
#pragma unroll
        for (int kj = 0; kj < 3; ++kj) {
            int ww = w + kj - 1;
            float xf = 0.f;
            if (hh >= 0 && hh < 56 && ww >= 0 && ww < 56)
                xf = bf2f(xvb[hh * 56 + ww]);
            acc += wb[(size_t)c_tab[g][ki * 3 + kj] * PIX] * xf;
        }
    }
    out[idx] = acc;
}

// ---------------------------------------------------------------------------
extern "C" void kernel_launch(void* const* d_in, const int* in_sizes, int n_in,
                              void* d_out, int out_size, void* d_ws, size_t ws_size,
                              hipStream_t stream) {
    (void)in_sizes; (void)n_in; (void)out_size; (void)ws_size;
    const float* x     = (const float*)d_in[0];
    const float* w_v   = (const float*)d_in[1];
    const float* w1    = (const float*)d_in[2];
    const float* gamma = (const float*)d_in[3];
    const float* beta  = (const float*)d_in[4];
    const float* w2    = (const float*)d_in[5];
    const float* b2    = (const float*)d_in[6];
    float* out = (float*)d_out;

    // workspace layout (~107 MB total)
    char* ws = (char*)d_ws;
    unsigned short* Wbig = (unsigned short*)ws;                    //    786,432 B
    unsigned short* xbf  = (unsigned short*)(ws + 786432);         // 25,690,112 B
    unsigned short* xv   = (unsigned short*)(ws + 26476544);       // 25,690,112 B
    float* y1    = (float*)(ws + 52166656);                        // 25,690,112 B
    float* stats = (float*)(ws + 77856768);                        //      2,048 B
    float* wgt   = (float*)(ws + 77858816);                        // 28,901,376 B

    cvt_x_kernel<<<12544, 256, 0, stream>>>(x, xbf);
    build_w_kernel<<<1536, 256, 0, stream>>>(w_v, w1, Wbig);
    gemm_kernel<<<392 * 12, 256, 0, stream>>>(xbf, Wbig, xv, y1);
    gn_stats_kernel<<<256, 256, 0, stream>>>(y1, stats);
    wgt_kernel<<<784, 256, 0, stream>>>(y1, stats, gamma, beta, w2, b2, wgt);
    final_kernel<<<50176, 256, 0, stream>>>(wgt, xv, out);
}

// Round 3
// 299.454 us; speedup vs baseline: 1.2540x; 1.2540x over previous
//
#include <hip/hip_runtime.h>

// Problem constants (b=8, H=W=56, cin=64, cout=64, cmid=32, k=3, G=4, gc=16)
// ALL inputs and the output are float32 (per reference setup_inputs).
// Internal GEMM runs in bf16 (2% rel threshold permits it; measured absmax 0.125).
#define BATCH 8
#define PIX   3136          // 56*56
#define CIN8  512           // cin*8
#define CMID8 256
#define KDIM  512

typedef short short8 __attribute__((ext_vector_type(8)));
typedef float f32x4 __attribute__((ext_vector_type(4)));

__constant__ int c_perms[8][8] = {
    {0, 1, 2, 3, 4, 5, 6, 7},
    {3, 0, 1, 2, 5, 6, 7, 4},
    {2, 3, 0, 1, 6, 7, 4, 5},
    {1, 2, 3, 0, 7, 4, 5, 6},
    {4, 5, 6, 7, 0, 1, 2, 3},
    {5, 6, 7, 4, 3, 0, 1, 2},
    {6, 7, 4, 5, 2, 3, 0, 1},
};
__constant__ int c_perm7[8] = {7, 4, 5, 6, 1, 2, 3, 0};

// TAB[g][p]: source tap (ki'*3+kj') in wgt for output tap p=ki*3+kj  [verified R1]
__constant__ int c_tab[8][9] = {
    {0, 1, 2, 3, 4, 5, 6, 7, 8},
    {2, 5, 8, 1, 4, 7, 0, 3, 6},
    {8, 7, 6, 5, 4, 3, 2, 1, 0},
    {6, 3, 0, 7, 4, 1, 8, 5, 2},
    {2, 1, 0, 5, 4, 3, 8, 7, 6},
    {8, 5, 2, 7, 4, 1, 6, 3, 0},
    {6, 7, 8, 3, 4, 5, 0, 1, 2},
    {0, 3, 6, 1, 4, 7, 2, 5, 8},
};

__device__ __forceinline__ float bf2f(unsigned short u) {
    union { unsigned int i; float f; } v;
    v.i = ((unsigned int)u) << 16;
    return v.f;
}
__device__ __forceinline__ unsigned short f2bf(float f) {
    union { float f; unsigned int u; } v;
    v.f = f;
    unsigned int u = v.u;
    u += 0x7FFFu + ((u >> 16) & 1u);   // RNE
    return (unsigned short)(u >> 16);
}

// ---------------------------------------------------------------------------
// K0a: convert x f32 -> bf16. 4 elems/thread.
// ---------------------------------------------------------------------------
__global__ __launch_bounds__(256) void cvt_x_kernel(
    const float* __restrict__ x, unsigned short* __restrict__ xbf)
{
    int i = (blockIdx.x * 256 + threadIdx.x) * 4;   // 12,845,056 exact
    float4 v = *(const float4*)(x + i);
    ushort2 lo = {f2bf(v.x), f2bf(v.y)};
    ushort2 hi = {f2bf(v.z), f2bf(v.w)};
    *(ushort2*)(xbf + i)     = lo;
    *(ushort2*)(xbf + i + 2) = hi;
}

// ---------------------------------------------------------------------------
// K0b: build 768x512 permuted weight matrix in bf16, k-contiguous.
// ---------------------------------------------------------------------------
__global__ __launch_bounds__(256) void build_w_kernel(
    const float* __restrict__ w_v, const float* __restrict__ w1,
    unsigned short* __restrict__ Wbig)
{
    int idx = blockIdx.x * 256 + threadIdx.x;     // 768*512 = 393216 exact
    int r = idx >> 9;
    int k = idx & 511;
    int i = k >> 3, f = k & 7;
    float v;
    if (r < 512) {
        int o = r >> 3, g = r & 7;
        int pf = (g < 7) ? c_perms[g][f] : c_perm7[f];
        v = w_v[(o * 64 + i) * 8 + pf];
    } else {
        int rr = r - 512;
        int o = rr >> 3, g = rr & 7;
        int pf = (g < 7) ? c_perms[g][f] : c_perm7[f];
        v = w1[(o * 64 + i) * 8 + pf];
    }
    Wbig[idx] = f2bf(v);
}

// ---------------------------------------------------------------------------
// K1: MFMA GEMM (unchanged from R1). D[row][pixel] = sum_k Wbig[row][k]*xbf[b][k][pixel]
// ---------------------------------------------------------------------------
#define LDK 40

__global__ __launch_bounds__(256) void gemm_kernel(
    const unsigned short* __restrict__ x,     // xbf [8][512][3136]
    const unsigned short* __restrict__ Wbig,  // [768][512]
    unsigned short* __restrict__ xv,          // [8][512][3136] bf16
    float* __restrict__ y1)                   // [8][256][3136] f32
{
    __shared__ unsigned short Wt[64 * LDK];
    __shared__ unsigned short Xt[64 * LDK];

    const int tid  = threadIdx.x;
    const int lane = tid & 63;
    const int wave = tid >> 6;

    const int flat = blockIdx.x;
    const int pt   = flat / 12;
    const int rt   = flat % 12;
    const int b    = pt / 49;
    const int p0   = (pt % 49) * 64;
    const int row0 = rt * 64;

    const unsigned short* xb = x + (size_t)b * CIN8 * PIX + p0;

    f32x4 acc[4];
#pragma unroll
    for (int i = 0; i < 4; ++i) acc[i] = (f32x4){0.f, 0.f, 0.f, 0.f};

    const int wm  = tid >> 2;
    const int wko = (tid & 3) * 8;
    const int xk  = tid >> 3;
    const int xn0 = (tid & 7) * 8;

    const int m16 = lane & 15;
    const int q8  = (lane >> 4) * 8;

    for (int kc = 0; kc < 16; ++kc) {
        const int k0 = kc * 32;
        {
            const unsigned short* src = Wbig + (size_t)(row0 + wm) * KDIM + (k0 + wko);
            *(uint4*)&Wt[wm * LDK + wko] = *(const uint4*)src;
        }
        {
            const unsigned short* src = xb + (size_t)(k0 + xk) * PIX + xn0;
            uint4 v = *(const uint4*)src;
            const unsigned short* vs = (const unsigned short*)&v;
#pragma unroll
            for (int j = 0; j < 8; ++j)
                Xt[(xn0 + j) * LDK + xk] = vs[j];
        }
        __syncthreads();
        short8 bfrag = *(const short8*)&Xt[(wave * 16 + m16) * LDK + q8];
#pragma unroll
        for (int mt = 0; mt < 4; ++mt) {
            short8 afrag = *(const short8*)&Wt[(mt * 16 + m16) * LDK + q8];
            acc[mt] = __builtin_amdgcn_mfma_f32_16x16x32_bf16(afrag, bfrag, acc[mt], 0, 0, 0);
        }
        __syncthreads();
    }

    const int n  = p0 + wave * 16 + m16;
    const int qm = (lane >> 4) * 4;
    if (row0 < 512) {
#pragma unroll
        for (int mt = 0; mt < 4; ++mt) {
            int m = row0 + mt * 16 + qm;
            size_t base = ((size_t)b * CIN8 + m) * PIX + n;
#pragma unroll
            for (int r = 0; r < 4; ++r)
                xv[base + (size_t)r * PIX] = f2bf(acc[mt][r]);
        }
    } else {
#pragma unroll
        for (int mt = 0; mt < 4; ++mt) {
            int m = (row0 - 512) + mt * 16 + qm;
            size_t base = ((size_t)b * CMID8 + m) * PIX + n;
#pragma unroll
            for (int r = 0; r < 4; ++r)
                y1[base + (size_t)r * PIX] = acc[mt][r];
        }
    }
}

// ---------------------------------------------------------------------------
// K2: GroupNorm stats (unchanged).
// ---------------------------------------------------------------------------
__global__ __launch_bounds__(256) void gn_stats_kernel(
    const float* __restrict__ y1, float* __restrict__ stats)
{
    const float* base = y1 + (size_t)blockIdx.x * 25088;
    float s = 0.f, ss = 0.f;
    for (int i = threadIdx.x; i < 25088; i += 256) {
        float v = base[i];
        s += v; ss += v * v;
    }
#pragma unroll
    for (int off = 32; off; off >>= 1) {
        s  += __shfl_down(s, off);
        ss += __shfl_down(ss, off);
    }
    __shared__ float red[8];
    int wave = threadIdx.x >> 6, lane = threadIdx.x & 63;
    if (lane == 0) { red[wave * 2] = s; red[wave * 2 + 1] = ss; }
    __syncthreads();
    if (threadIdx.x == 0) {
        float S  = red[0] + red[2] + red[4] + red[6];
        float SS = red[1] + red[3] + red[5] + red[7];
        float mean = S * (1.f / 25088.f);
        float var  = SS * (1.f / 25088.f) - mean * mean;
        stats[blockIdx.x * 2]     = mean;
        stats[blockIdx.x * 2 + 1] = rsqrtf(var + 1e-5f);
    }
}

// ---------------------------------------------------------------------------
// K3: normalize + ReLU + 36x32 matmul -> wgt[b][g][o2][p] (unchanged).
// ---------------------------------------------------------------------------
__global__ __launch_bounds__(256) void wgt_kernel(
    const float* __restrict__ y1, const float* __restrict__ stats,
    const float* __restrict__ gamma, const float* __restrict__ beta,
    const float* __restrict__ w2, const float* __restrict__ b2,
    float* __restrict__ wgt)
{
    __shared__ float w2s[36 * 32];
    __shared__ float b2s[36];
    for (int i = threadIdx.x; i < 36 * 32; i += 256) w2s[i] = w2[i];
    if (threadIdx.x < 36) b2s[threadIdx.x] = b2[threadIdx.x];
    __syncthreads();

    int idx = blockIdx.x * 256 + threadIdx.x;
    int p  = idx % PIX;
    int bg = idx / PIX;
    int b = bg >> 3, g = bg & 7;

    float t[32];
#pragma unroll
    for (int i = 0; i < 32; ++i) {
        float mean = stats[(b * 32 + i) * 2];
        float rstd = stats[(b * 32 + i) * 2 + 1];
        float ga = gamma[i * 8 + g];
        float be = beta[i * 8 + g];
        float v = y1[((size_t)(b * CMID8 + i * 8 + g)) * PIX + p];
        v = (v - mean) * rstd * ga + be;
        t[i] = v > 0.f ? v : 0.f;
    }
    size_t ob = (size_t)bg * 36 * PIX + p;
    for (int o2 = 0; o2 < 36; ++o2) {
        float a = b2s[o2];
#pragma unroll
        for (int i = 0; i < 32; ++i) a += w2s[o2 * 32 + i] * t[i];
        wgt[ob + (size_t)o2 * PIX] = a;
    }
}

// ---------------------------------------------------------------------------
// K4 (RESTRUCTURED): thread = (b,g,gidx,p), computes ALL 16 cc channels.
// 9 wgt taps + masks loaded once; inner cc loop = 9 bf16 loads + 9 FMA + store.
// grid: 256 combos x 13 pixel-blocks; guard p < PIX.
// ---------------------------------------------------------------------------
__global__ __launch_bounds__(256) void final_kernel(
    const float* __restrict__ wgt, const unsigned short* __restrict__ xv,
    float* __restrict__ out)
{
    const int combo = blockIdx.x / 13;           // b*32 + g*4 + gidx
    const int p     = (blockIdx.x % 13) * 256 + threadIdx.x;
    if (p >= PIX) return;
    const int b    = combo >> 5;
    const int g    = (combo >> 2) & 7;
    const int gidx = combo & 3;
    const int h = p / 56, w = p % 56;

    // load 9 wgt taps for this pixel (coalesced, stride PIX)
    const float* wb = wgt + ((size_t)((b * 8 + g) * 36 + gidx * 9)) * PIX + p;
    float wt[9];
#pragma unroll
    for (int t = 0; t < 9; ++t) wt[t] = wb[(size_t)t * PIX];

    // per-window-tap: remapped weight (0 if out of bounds) + safe offset
    float wr[9];
    int   off[9];
#pragma unroll
    for (int t = 0; t < 9; ++t) {
        int ki = t / 3, kj = t % 3;
        int hh = h + ki - 1, ww = w + kj - 1;
        bool valid = (hh >= 0) & (hh < 56) & (ww >= 0) & (ww < 56);
        wr[t]  = valid ? wt[c_tab[g][t]] : 0.f;
        off[t] = valid ? (hh * 56 + ww) : 0;
    }

    // cc loop: channel ch = (gidx*16+cc)*8 + g, stride 8*PIX between cc
    const unsigned short* xc = xv + ((size_t)b * CIN8 + (gidx * 16) * 8 + g) * PIX;
    float* ob = out + ((size_t)b * CIN8 + (gidx * 16) * 8 + g) * PIX + p;
#pragma unroll 4
    for (int cc = 0; cc < 16; ++cc) {
        float a = 0.f;
#pragma unroll
        for (int t = 0; t < 9; ++t)
            a = fmaf(wr[t], bf2f(xc[off[t]]), a);
        ob[(size_t)cc * 8 * PIX] = a;
        xc += (size_t)8 * PIX;
    }
}

// ---------------------------------------------------------------------------
extern "C" void kernel_launch(void* const* d_in, const int* in_sizes, int n_in,
                              void* d_out, int out_size, void* d_ws, size_t ws_size,
                              hipStream_t stream) {
    (void)in_sizes; (void)n_in; (void)out_size; (void)ws_size;
    const float* x     = (const float*)d_in[0];
    const float* w_v   = (const float*)d_in[1];
    const float* w1    = (const float*)d_in[2];
    const float* gamma = (const float*)d_in[3];
    const float* beta  = (const float*)d_in[4];
    const float* w2    = (const float*)d_in[5];
    const float* b2    = (const float*)d_in[6];
    float* out = (float*)d_out;

    char* ws = (char*)d_ws;
    unsigned short* Wbig = (unsigned short*)ws;                    //    786,432 B
    unsigned short* xbf  = (unsigned short*)(ws + 786432);         // 25,690,112 B
    unsigned short* xv   = (unsigned short*)(ws + 26476544);       // 25,690,112 B
    float* y1    = (float*)(ws + 52166656);                        // 25,690,112 B
    float* stats = (float*)(ws + 77856768);                        //      2,048 B
    float* wgt   = (float*)(ws + 77858816);                        // 28,901,376 B

    cvt_x_kernel<<<12544, 256, 0, stream>>>(x, xbf);
    build_w_kernel<<<1536, 256, 0, stream>>>(w_v, w1, Wbig);
    gemm_kernel<<<392 * 12, 256, 0, stream>>>(xbf, Wbig, xv, y1);
    gn_stats_kernel<<<256, 256, 0, stream>>>(y1, stats);
    wgt_kernel<<<784, 256, 0, stream>>>(y1, stats, gamma, beta, w2, b2, wgt);
    final_kernel<<<256 * 13, 256, 0, stream>>>(wgt, xv, out);
}

// Round 4
// 248.481 us; speedup vs baseline: 1.5112x; 1.2051x over previous
//
#include <hip/hip_runtime.h>

// Problem constants (b=8, H=W=56, cin=64, cout=64, cmid=32, k=3, G=4, gc=16)
// ALL inputs and the output are float32. Internal GEMM in bf16 (absmax 0.125 vs thr 0.5275).
#define BATCH 8
#define PIX   3136          // 56*56
#define CIN8  512           // cin*8
#define CMID8 256
#define KDIM  512

typedef short short8 __attribute__((ext_vector_type(8)));
typedef float f32x4 __attribute__((ext_vector_type(4)));

__constant__ int c_perms[8][8] = {
    {0, 1, 2, 3, 4, 5, 6, 7},
    {3, 0, 1, 2, 5, 6, 7, 4},
    {2, 3, 0, 1, 6, 7, 4, 5},
    {1, 2, 3, 0, 7, 4, 5, 6},
    {4, 5, 6, 7, 0, 1, 2, 3},
    {5, 6, 7, 4, 3, 0, 1, 2},
    {6, 7, 4, 5, 2, 3, 0, 1},
};
__constant__ int c_perm7[8] = {7, 4, 5, 6, 1, 2, 3, 0};

// TAB[g][p]: source tap (ki'*3+kj') in wgt for output tap p=ki*3+kj  [verified R1]
__constant__ int c_tab[8][9] = {
    {0, 1, 2, 3, 4, 5, 6, 7, 8},
    {2, 5, 8, 1, 4, 7, 0, 3, 6},
    {8, 7, 6, 5, 4, 3, 2, 1, 0},
    {6, 3, 0, 7, 4, 1, 8, 5, 2},
    {2, 1, 0, 5, 4, 3, 8, 7, 6},
    {8, 5, 2, 7, 4, 1, 6, 3, 0},
    {6, 7, 8, 3, 4, 5, 0, 1, 2},
    {0, 3, 6, 1, 4, 7, 2, 5, 8},
};

__device__ __forceinline__ float bf2f(unsigned short u) {
    union { unsigned int i; float f; } v;
    v.i = ((unsigned int)u) << 16;
    return v.f;
}
__device__ __forceinline__ unsigned short f2bf(float f) {
    union { float f; unsigned int u; } v;
    v.f = f;
    unsigned int u = v.u;
    u += 0x7FFFu + ((u >> 16) & 1u);   // RNE
    return (unsigned short)(u >> 16);
}

// ---------------------------------------------------------------------------
// K0a: fused convert + TRANSPOSE: x[b][k][p] f32 -> xbfT[b][p][k] bf16.
// Tile 64k x 64p via LDS (LDT=70 pad: write 2-cyc-ish, read 2-way free).
// ---------------------------------------------------------------------------
#define LDT 70
__global__ __launch_bounds__(256) void cvt_t_kernel(
    const float* __restrict__ x, unsigned short* __restrict__ xbfT)
{
    __shared__ unsigned short T[64 * LDT];
    const int flat = blockIdx.x;            // 8 * 49 * 8 = 3136 blocks
    const int kt = flat & 7;
    const int pt = (flat >> 3) % 49;
    const int b  = flat / (49 * 8);
    const int k0 = kt * 64, p0 = pt * 64;

    const float* xb = x + ((size_t)b * CIN8 + k0) * PIX + p0;
    const int kl = threadIdx.x >> 4;        // 0..15
    const int pl = (threadIdx.x & 15) * 4;  // 0..60
#pragma unroll
    for (int pass = 0; pass < 4; ++pass) {
        int kk = kl + pass * 16;
        float4 v = *(const float4*)(xb + (size_t)kk * PIX + pl);
        ushort2 lo = {f2bf(v.x), f2bf(v.y)};
        ushort2 hi = {f2bf(v.z), f2bf(v.w)};
        *(ushort2*)&T[kk * LDT + pl]     = lo;
        *(ushort2*)&T[kk * LDT + pl + 2] = hi;
    }
    __syncthreads();
    const int prow = threadIdx.x >> 2;        // 0..63
    const int kc8  = (threadIdx.x & 3) * 8;   // 0,8,16,24
    unsigned short* ob = xbfT + ((size_t)b * PIX + p0 + prow) * KDIM + k0;
#pragma unroll
    for (int pass = 0; pass < 2; ++pass) {
        int kk = kc8 + pass * 32;
        unsigned short tmp[8];
#pragma unroll
        for (int j = 0; j < 8; ++j) tmp[j] = T[(kk + j) * LDT + prow];
        *(uint4*)(ob + kk) = *(const uint4*)tmp;
    }
}

// ---------------------------------------------------------------------------
// K0b: build 768x512 permuted weight matrix in bf16, k-contiguous.
// ---------------------------------------------------------------------------
__global__ __launch_bounds__(256) void build_w_kernel(
    const float* __restrict__ w_v, const float* __restrict__ w1,
    unsigned short* __restrict__ Wbig)
{
    int idx = blockIdx.x * 256 + threadIdx.x;     // 768*512 = 393216 exact
    int r = idx >> 9;
    int k = idx & 511;
    int i = k >> 3, f = k & 7;
    float v;
    if (r < 512) {
        int o = r >> 3, g = r & 7;
        int pf = (g < 7) ? c_perms[g][f] : c_perm7[f];
        v = w_v[(o * 64 + i) * 8 + pf];
    } else {
        int rr = r - 512;
        int o = rr >> 3, g = rr & 7;
        int pf = (g < 7) ? c_perms[g][f] : c_perm7[f];
        v = w1[(o * 64 + i) * 8 + pf];
    }
    Wbig[idx] = f2bf(v);
}

// ---------------------------------------------------------------------------
// K1: MFMA GEMM. D[row][pixel] = sum_k Wbig[row][k] * xT[b][pixel][k]
// Both operands k-contiguous: staging = uint4 load -> b128 LDS write (no
// transpose in loop; LDK=40 pad -> bank-packed b128 on both sides).
// ---------------------------------------------------------------------------
#define LDK 40

__global__ __launch_bounds__(256) void gemm_kernel(
    const unsigned short* __restrict__ xT,    // [8][3136][512]
    const unsigned short* __restrict__ Wbig,  // [768][512]
    unsigned short* __restrict__ xv,          // [8][512][3136] bf16
    float* __restrict__ y1)                   // [8][256][3136] f32
{
    __shared__ unsigned short Wt[64 * LDK];
    __shared__ unsigned short Xt[64 * LDK];

    const int tid  = threadIdx.x;
    const int lane = tid & 63;
    const int wave = tid >> 6;

    const int flat = blockIdx.x;       // pt*12 + rt (rt fast: row tiles share x tile)
    const int pt   = flat / 12;
    const int rt   = flat % 12;
    const int b    = pt / 49;
    const int p0   = (pt % 49) * 64;
    const int row0 = rt * 64;

    const unsigned short* xb = xT + ((size_t)b * PIX + p0) * KDIM;

    f32x4 acc[4];
#pragma unroll
    for (int i = 0; i < 4; ++i) acc[i] = (f32x4){0.f, 0.f, 0.f, 0.f};

    const int srow = tid >> 2;           // 0..63 (both tiles)
    const int sc   = (tid & 3) * 8;      // k chunk {0,8,16,24}

    const int m16 = lane & 15;
    const int q8  = (lane >> 4) * 8;

    const unsigned short* wsrc = Wbig + (size_t)(row0 + srow) * KDIM + sc;
    const unsigned short* xsrc = xb + (size_t)srow * KDIM + sc;

    for (int kc = 0; kc < 16; ++kc) {
        const int k0 = kc * 32;
        *(uint4*)&Wt[srow * LDK + sc] = *(const uint4*)(wsrc + k0);
        *(uint4*)&Xt[srow * LDK + sc] = *(const uint4*)(xsrc + k0);
        __syncthreads();
        short8 bfrag = *(const short8*)&Xt[(wave * 16 + m16) * LDK + q8];
#pragma unroll
        for (int mt = 0; mt < 4; ++mt) {
            short8 afrag = *(const short8*)&Wt[(mt * 16 + m16) * LDK + q8];
            acc[mt] = __builtin_amdgcn_mfma_f32_16x16x32_bf16(afrag, bfrag, acc[mt], 0, 0, 0);
        }
        __syncthreads();
    }

    // epilogue: C/D layout col(n)=lane&15, row(m)=(lane>>4)*4+reg  [m89/m91]
    const int n  = p0 + wave * 16 + m16;
    const int qm = (lane >> 4) * 4;
    if (row0 < 512) {
#pragma unroll
        for (int mt = 0; mt < 4; ++mt) {
            int m = row0 + mt * 16 + qm;
            size_t base = ((size_t)b * CIN8 + m) * PIX + n;
#pragma unroll
            for (int r = 0; r < 4; ++r)
                xv[base + (size_t)r * PIX] = f2bf(acc[mt][r]);
        }
    } else {
#pragma unroll
        for (int mt = 0; mt < 4; ++mt) {
            int m = (row0 - 512) + mt * 16 + qm;
            size_t base = ((size_t)b * CMID8 + m) * PIX + n;
#pragma unroll
            for (int r = 0; r < 4; ++r)
                y1[base + (size_t)r * PIX] = acc[mt][r];
        }
    }
}

// ---------------------------------------------------------------------------
// K2: GroupNorm stats (unchanged).
// ---------------------------------------------------------------------------
__global__ __launch_bounds__(256) void gn_stats_kernel(
    const float* __restrict__ y1, float* __restrict__ stats)
{
    const float* base = y1 + (size_t)blockIdx.x * 25088;
    float s = 0.f, ss = 0.f;
    for (int i = threadIdx.x; i < 25088; i += 256) {
        float v = base[i];
        s += v; ss += v * v;
    }
#pragma unroll
    for (int off = 32; off; off >>= 1) {
        s  += __shfl_down(s, off);
        ss += __shfl_down(ss, off);
    }
    __shared__ float red[8];
    int wave = threadIdx.x >> 6, lane = threadIdx.x & 63;
    if (lane == 0) { red[wave * 2] = s; red[wave * 2 + 1] = ss; }
    __syncthreads();
    if (threadIdx.x == 0) {
        float S  = red[0] + red[2] + red[4] + red[6];
        float SS = red[1] + red[3] + red[5] + red[7];
        float mean = S * (1.f / 25088.f);
        float var  = SS * (1.f / 25088.f) - mean * mean;
        stats[blockIdx.x * 2]     = mean;
        stats[blockIdx.x * 2 + 1] = rsqrtf(var + 1e-5f);
    }
}

// ---------------------------------------------------------------------------
// K3: normalize + ReLU + 36x32 matmul -> wgt[b][g][o2][p] (unchanged).
// ---------------------------------------------------------------------------
__global__ __launch_bounds__(256) void wgt_kernel(
    const float* __restrict__ y1, const float* __restrict__ stats,
    const float* __restrict__ gamma, const float* __restrict__ beta,
    const float* __restrict__ w2, const float* __restrict__ b2,
    float* __restrict__ wgt)
{
    __shared__ float w2s[36 * 32];
    __shared__ float b2s[36];
    for (int i = threadIdx.x; i < 36 * 32; i += 256) w2s[i] = w2[i];
    if (threadIdx.x < 36) b2s[threadIdx.x] = b2[threadIdx.x];
    __syncthreads();

    int idx = blockIdx.x * 256 + threadIdx.x;
    int p  = idx % PIX;
    int bg = idx / PIX;
    int b = bg >> 3, g = bg & 7;

    float t[32];
#pragma unroll
    for (int i = 0; i < 32; ++i) {
        float mean = stats[(b * 32 + i) * 2];
        float rstd = stats[(b * 32 + i) * 2 + 1];
        float ga = gamma[i * 8 + g];
        float be = beta[i * 8 + g];
        float v = y1[((size_t)(b * CMID8 + i * 8 + g)) * PIX + p];
        v = (v - mean) * rstd * ga + be;
        t[i] = v > 0.f ? v : 0.f;
    }
    size_t ob = (size_t)bg * 36 * PIX + p;
    for (int o2 = 0; o2 < 36; ++o2) {
        float a = b2s[o2];
#pragma unroll
        for (int i = 0; i < 32; ++i) a += w2s[o2 * 32 + i] * t[i];
        wgt[ob + (size_t)o2 * PIX] = a;
    }
}

// ---------------------------------------------------------------------------
// K4: thread = (b,g,gidx,p), computes all 16 cc channels (unchanged from R2).
// ---------------------------------------------------------------------------
__global__ __launch_bounds__(256) void final_kernel(
    const float* __restrict__ wgt, const unsigned short* __restrict__ xv,
    float* __restrict__ out)
{
    const int combo = blockIdx.x / 13;           // b*32 + g*4 + gidx
    const int p     = (blockIdx.x % 13) * 256 + threadIdx.x;
    if (p >= PIX) return;
    const int b    = combo >> 5;
    const int g    = (combo >> 2) & 7;
    const int gidx = combo & 3;
    const int h = p / 56, w = p % 56;

    const float* wb = wgt + ((size_t)((b * 8 + g) * 36 + gidx * 9)) * PIX + p;
    float wt[9];
#pragma unroll
    for (int t = 0; t < 9; ++t) wt[t] = wb[(size_t)t * PIX];

    float wr[9];
    int   off[9];
#pragma unroll
    for (int t = 0; t < 9; ++t) {
        int ki = t / 3, kj = t % 3;
        int hh = h + ki - 1, ww = w + kj - 1;
        bool valid = (hh >= 0) & (hh < 56) & (ww >= 0) & (ww < 56);
        wr[t]  = valid ? wt[c_tab[g][t]] : 0.f;
        off[t] = valid ? (hh * 56 + ww) : 0;
    }

    const unsigned short* xc = xv + ((size_t)b * CIN8 + (gidx * 16) * 8 + g) * PIX;
    float* ob = out + ((size_t)b * CIN8 + (gidx * 16) * 8 + g) * PIX + p;
#pragma unroll 4
    for (int cc = 0; cc < 16; ++cc) {
        float a = 0.f;
#pragma unroll
        for (int t = 0; t < 9; ++t)
            a = fmaf(wr[t], bf2f(xc[off[t]]), a);
        ob[(size_t)cc * 8 * PIX] = a;
        xc += (size_t)8 * PIX;
    }
}

// ---------------------------------------------------------------------------
extern "C" void kernel_launch(void* const* d_in, const int* in_sizes, int n_in,
                              void* d_out, int out_size, void* d_ws, size_t ws_size,
                              hipStream_t stream) {
    (void)in_sizes; (void)n_in; (void)out_size; (void)ws_size;
    const float* x     = (const float*)d_in[0];
    const float* w_v   = (const float*)d_in[1];
    const float* w1    = (const float*)d_in[2];
    const float* gamma = (const float*)d_in[3];
    const float* beta  = (const float*)d_in[4];
    const float* w2    = (const float*)d_in[5];
    const float* b2    = (const float*)d_in[6];
    float* out = (float*)d_out;

    char* ws = (char*)d_ws;
    unsigned short* Wbig = (unsigned short*)ws;                    //    786,432 B
    unsigned short* xbfT = (unsigned short*)(ws + 786432);         // 25,690,112 B  [b][p][k]
    unsigned short* xv   = (unsigned short*)(ws + 26476544);       // 25,690,112 B  [b][ch][p]
    float* y1    = (float*)(ws + 52166656);                        // 25,690,112 B
    float* stats = (float*)(ws + 77856768);                        //      2,048 B
    float* wgt   = (float*)(ws + 77858816);                        // 28,901,376 B

    cvt_t_kernel<<<3136, 256, 0, stream>>>(x, xbfT);
    build_w_kernel<<<1536, 256, 0, stream>>>(w_v, w1, Wbig);
    gemm_kernel<<<392 * 12, 256, 0, stream>>>(xbfT, Wbig, xv, y1);
    gn_stats_kernel<<<256, 256, 0, stream>>>(y1, stats);
    wgt_kernel<<<784, 256, 0, stream>>>(y1, stats, gamma, beta, w2, b2, wgt);
    final_kernel<<<256 * 13, 256, 0, stream>>>(wgt, xv, out);
}

// Round 5
// 245.834 us; speedup vs baseline: 1.5275x; 1.0108x over previous
//
#include <hip/hip_runtime.h>

// Problem constants (b=8, H=W=56, cin=64, cout=64, cmid=32, k=3, G=4, gc=16)
// ALL inputs and the output are float32. Internal GEMM in bf16 (absmax 0.125 vs thr 0.5275).
#define BATCH 8
#define PIX   3136          // 56*56
#define CIN8  512           // cin*8
#define CMID8 256
#define KDIM  512
#define NCOL  25088         // 8*3136 flat columns

typedef short short8 __attribute__((ext_vector_type(8)));
typedef float f32x4 __attribute__((ext_vector_type(4)));

__constant__ int c_perms[8][8] = {
    {0, 1, 2, 3, 4, 5, 6, 7},
    {3, 0, 1, 2, 5, 6, 7, 4},
    {2, 3, 0, 1, 6, 7, 4, 5},
    {1, 2, 3, 0, 7, 4, 5, 6},
    {4, 5, 6, 7, 0, 1, 2, 3},
    {5, 6, 7, 4, 3, 0, 1, 2},
    {6, 7, 4, 5, 2, 3, 0, 1},
};
__constant__ int c_perm7[8] = {7, 4, 5, 6, 1, 2, 3, 0};

// TAB[g][p]: source tap (ki'*3+kj') in wgt for output tap p=ki*3+kj  [verified R1]
__constant__ int c_tab[8][9] = {
    {0, 1, 2, 3, 4, 5, 6, 7, 8},
    {2, 5, 8, 1, 4, 7, 0, 3, 6},
    {8, 7, 6, 5, 4, 3, 2, 1, 0},
    {6, 3, 0, 7, 4, 1, 8, 5, 2},
    {2, 1, 0, 5, 4, 3, 8, 7, 6},
    {8, 5, 2, 7, 4, 1, 6, 3, 0},
    {6, 7, 8, 3, 4, 5, 0, 1, 2},
    {0, 3, 6, 1, 4, 7, 2, 5, 8},
};

__device__ __forceinline__ float bf2f(unsigned short u) {
    union { unsigned int i; float f; } v;
    v.i = ((unsigned int)u) << 16;
    return v.f;
}
__device__ __forceinline__ unsigned short f2bf(float f) {
    union { float f; unsigned int u; } v;
    v.f = f;
    unsigned int u = v.u;
    u += 0x7FFFu + ((u >> 16) & 1u);   // RNE
    return (unsigned short)(u >> 16);
}

// ---------------------------------------------------------------------------
// K0a: fused convert + TRANSPOSE: x[b][k][p] f32 -> xbfT[b][p][k] bf16.
// (unchanged from R3)
// ---------------------------------------------------------------------------
#define LDT 70
__global__ __launch_bounds__(256) void cvt_t_kernel(
    const float* __restrict__ x, unsigned short* __restrict__ xbfT)
{
    __shared__ unsigned short T[64 * LDT];
    const int flat = blockIdx.x;            // 8 * 49 * 8 = 3136 blocks
    const int kt = flat & 7;
    const int pt = (flat >> 3) % 49;
    const int b  = flat / (49 * 8);
    const int k0 = kt * 64, p0 = pt * 64;

    const float* xb = x + ((size_t)b * CIN8 + k0) * PIX + p0;
    const int kl = threadIdx.x >> 4;        // 0..15
    const int pl = (threadIdx.x & 15) * 4;  // 0..60
#pragma unroll
    for (int pass = 0; pass < 4; ++pass) {
        int kk = kl + pass * 16;
        float4 v = *(const float4*)(xb + (size_t)kk * PIX + pl);
        ushort2 lo = {f2bf(v.x), f2bf(v.y)};
        ushort2 hi = {f2bf(v.z), f2bf(v.w)};
        *(ushort2*)&T[kk * LDT + pl]     = lo;
        *(ushort2*)&T[kk * LDT + pl + 2] = hi;
    }
    __syncthreads();
    const int prow = threadIdx.x >> 2;        // 0..63
    const int kc8  = (threadIdx.x & 3) * 8;   // 0,8,16,24
    unsigned short* ob = xbfT + ((size_t)b * PIX + p0 + prow) * KDIM + k0;
#pragma unroll
    for (int pass = 0; pass < 2; ++pass) {
        int kk = kc8 + pass * 32;
        unsigned short tmp[8];
#pragma unroll
        for (int j = 0; j < 8; ++j) tmp[j] = T[(kk + j) * LDT + prow];
        *(uint4*)(ob + kk) = *(const uint4*)tmp;
    }
}

// ---------------------------------------------------------------------------
// K0b: build 768x512 permuted weight matrix in bf16, k-contiguous. (unchanged)
// ---------------------------------------------------------------------------
__global__ __launch_bounds__(256) void build_w_kernel(
    const float* __restrict__ w_v, const float* __restrict__ w1,
    unsigned short* __restrict__ Wbig)
{
    int idx = blockIdx.x * 256 + threadIdx.x;     // 768*512 = 393216 exact
    int r = idx >> 9;
    int k = idx & 511;
    int i = k >> 3, f = k & 7;
    float v;
    if (r < 512) {
        int o = r >> 3, g = r & 7;
        int pf = (g < 7) ? c_perms[g][f] : c_perm7[f];
        v = w_v[(o * 64 + i) * 8 + pf];
    } else {
        int rr = r - 512;
        int o = rr >> 3, g = rr & 7;
        int pf = (g < 7) ? c_perms[g][f] : c_perm7[f];
        v = w1[(o * 64 + i) * 8 + pf];
    }
    Wbig[idx] = f2bf(v);
}

// ---------------------------------------------------------------------------
// K1 (REWRITTEN): 128x128-tile MFMA GEMM over flat columns P in [0,25088).
// 4 waves in 2x2, each 64x64 (acc[4][4]) -> LDS-read ratio 0.5 b128/MFMA.
// Grid 6 x 200 (200 % 8 == 0): flat = rt*200+pt -> XCD = pt%8, so all 6
// row-tiles of a pixel tile share one XCD's L2 (xT fetched ~once).
// ---------------------------------------------------------------------------
#define LDK 40

__global__ __launch_bounds__(256) void gemm_kernel(
    const unsigned short* __restrict__ xT,    // [8][3136][512] = [25088][512]
    const unsigned short* __restrict__ Wbig,  // [768][512]
    unsigned short* __restrict__ xv,          // [8][512][3136] bf16
    float* __restrict__ y1)                   // [8][256][3136] f32
{
    __shared__ unsigned short Wt[128 * LDK];
    __shared__ unsigned short Xt[128 * LDK];

    const int flat = blockIdx.x;        // 6*200 = 1200
    const int rt   = flat / 200;
    const int pt   = flat % 200;
    if (pt >= 196) return;              // whole block exits together
    const int row0 = rt * 128;
    const int P0   = pt * 128;

    const int tid  = threadIdx.x;
    const int lane = tid & 63;
    const int wave = tid >> 6;
    const int wm   = wave & 1;          // M half
    const int wn   = wave >> 1;         // N half

    f32x4 acc[4][4];
#pragma unroll
    for (int i = 0; i < 4; ++i)
#pragma unroll
        for (int j = 0; j < 4; ++j) acc[i][j] = (f32x4){0.f, 0.f, 0.f, 0.f};

    // staging: 128 rows x 32 k per tile; thread -> row tid>>1, k-half (tid&1)*16
    const int srow = tid >> 1;
    const int sk   = (tid & 1) << 4;
    const unsigned short* wsrc = Wbig + (size_t)(row0 + srow) * KDIM + sk;
    const unsigned short* xsrc = xT + ((size_t)(P0 + srow)) * KDIM + sk;
    unsigned short* wdst = &Wt[srow * LDK + sk];
    unsigned short* xdst = &Xt[srow * LDK + sk];

    const int m16 = lane & 15;
    const int q8  = (lane >> 4) * 8;

    for (int kc = 0; kc < 16; ++kc) {
        const int k0 = kc * 32;
        *(uint4*)wdst       = *(const uint4*)(wsrc + k0);
        *(uint4*)(wdst + 8) = *(const uint4*)(wsrc + k0 + 8);
        *(uint4*)xdst       = *(const uint4*)(xsrc + k0);
        *(uint4*)(xdst + 8) = *(const uint4*)(xsrc + k0 + 8);
        __syncthreads();

        short8 bfrag[4];
#pragma unroll
        for (int nt = 0; nt < 4; ++nt)
            bfrag[nt] = *(const short8*)&Xt[(wn * 64 + nt * 16 + m16) * LDK + q8];
#pragma unroll
        for (int mt = 0; mt < 4; ++mt) {
            short8 afrag = *(const short8*)&Wt[(wm * 64 + mt * 16 + m16) * LDK + q8];
#pragma unroll
            for (int nt = 0; nt < 4; ++nt)
                acc[mt][nt] = __builtin_amdgcn_mfma_f32_16x16x32_bf16(
                    afrag, bfrag[nt], acc[mt][nt], 0, 0, 0);
        }
        __syncthreads();
    }

    // epilogue: C/D layout col(n)=lane&15, row(m)=(lane>>4)*4+reg  [m89/m91]
    const int qm = (lane >> 4) * 4;
#pragma unroll
    for (int nt = 0; nt < 4; ++nt) {
        const int col = P0 + wn * 64 + nt * 16 + m16;   // < 25088
        const int bb  = col / PIX;
        const int pp  = col - bb * PIX;
        if (row0 < 512) {
            unsigned short* dst = xv + ((size_t)bb * CIN8) * PIX + pp;
#pragma unroll
            for (int mt = 0; mt < 4; ++mt) {
                const int m = row0 + wm * 64 + mt * 16 + qm;
#pragma unroll
                for (int r = 0; r < 4; ++r)
                    dst[(size_t)(m + r) * PIX] = f2bf(acc[mt][nt][r]);
            }
        } else {
            float* dst = y1 + ((size_t)bb * CMID8) * PIX + pp;
#pragma unroll
            for (int mt = 0; mt < 4; ++mt) {
                const int m = (row0 - 512) + wm * 64 + mt * 16 + qm;
#pragma unroll
                for (int r = 0; r < 4; ++r)
                    dst[(size_t)(m + r) * PIX] = acc[mt][nt][r];
            }
        }
    }
}

// ---------------------------------------------------------------------------
// K2: GroupNorm stats (unchanged).
// ---------------------------------------------------------------------------
__global__ __launch_bounds__(256) void gn_stats_kernel(
    const float* __restrict__ y1, float* __restrict__ stats)
{
    const float* base = y1 + (size_t)blockIdx.x * 25088;
    float s = 0.f, ss = 0.f;
    for (int i = threadIdx.x; i < 25088; i += 256) {
        float v = base[i];
        s += v; ss += v * v;
    }
#pragma unroll
    for (int off = 32; off; off >>= 1) {
        s  += __shfl_down(s, off);
        ss += __shfl_down(ss, off);
    }
    __shared__ float red[8];
    int wave = threadIdx.x >> 6, lane = threadIdx.x & 63;
    if (lane == 0) { red[wave * 2] = s; red[wave * 2 + 1] = ss; }
    __syncthreads();
    if (threadIdx.x == 0) {
        float S  = red[0] + red[2] + red[4] + red[6];
        float SS = red[1] + red[3] + red[5] + red[7];
        float mean = S * (1.f / 25088.f);
        float var  = SS * (1.f / 25088.f) - mean * mean;
        stats[blockIdx.x * 2]     = mean;
        stats[blockIdx.x * 2 + 1] = rsqrtf(var + 1e-5f);
    }
}

// ---------------------------------------------------------------------------
// K3: normalize + ReLU + 36x32 matmul -> wgt[b][g][o2][p] (unchanged).
// ---------------------------------------------------------------------------
__global__ __launch_bounds__(256) void wgt_kernel(
    const float* __restrict__ y1, const float* __restrict__ stats,
    const float* __restrict__ gamma, const float* __restrict__ beta,
    const float* __restrict__ w2, const float* __restrict__ b2,
    float* __restrict__ wgt)
{
    __shared__ float w2s[36 * 32];
    __shared__ float b2s[36];
    for (int i = threadIdx.x; i < 36 * 32; i += 256) w2s[i] = w2[i];
    if (threadIdx.x < 36) b2s[threadIdx.x] = b2[threadIdx.x];
    __syncthreads();

    int idx = blockIdx.x * 256 + threadIdx.x;
    int p  = idx % PIX;
    int bg = idx / PIX;
    int b = bg >> 3, g = bg & 7;

    float t[32];
#pragma unroll
    for (int i = 0; i < 32; ++i) {
        float mean = stats[(b * 32 + i) * 2];
        float rstd = stats[(b * 32 + i) * 2 + 1];
        float ga = gamma[i * 8 + g];
        float be = beta[i * 8 + g];
        float v = y1[((size_t)(b * CMID8 + i * 8 + g)) * PIX + p];
        v = (v - mean) * rstd * ga + be;
        t[i] = v > 0.f ? v : 0.f;
    }
    size_t ob = (size_t)bg * 36 * PIX + p;
    for (int o2 = 0; o2 < 36; ++o2) {
        float a = b2s[o2];
#pragma unroll
        for (int i = 0; i < 32; ++i) a += w2s[o2 * 32 + i] * t[i];
        wgt[ob + (size_t)o2 * PIX] = a;
    }
}

// ---------------------------------------------------------------------------
// K4: thread = (b,g,gidx,p), computes all 16 cc channels (unchanged).
// ---------------------------------------------------------------------------
__global__ __launch_bounds__(256) void final_kernel(
    const float* __restrict__ wgt, const unsigned short* __restrict__ xv,
    float* __restrict__ out)
{
    const int combo = blockIdx.x / 13;           // b*32 + g*4 + gidx
    const int p     = (blockIdx.x % 13) * 256 + threadIdx.x;
    if (p >= PIX) return;
    const int b    = combo >> 5;
    const int g    = (combo >> 2) & 7;
    const int gidx = combo & 3;
    const int h = p / 56, w = p % 56;

    const float* wb = wgt + ((size_t)((b * 8 + g) * 36 + gidx * 9)) * PIX + p;
    float wt[9];
#pragma unroll
    for (int t = 0; t < 9; ++t) wt[t] = wb[(size_t)t * PIX];

    float wr[9];
    int   off[9];
#pragma unroll
    for (int t = 0; t < 9; ++t) {
        int ki = t / 3, kj = t % 3;
        int hh = h + ki - 1, ww = w + kj - 1;
        bool valid = (hh >= 0) & (hh < 56) & (ww >= 0) & (ww < 56);
        wr[t]  = valid ? wt[c_tab[g][t]] : 0.f;
        off[t] = valid ? (hh * 56 + ww) : 0;
    }

    const unsigned short* xc = xv + ((size_t)b * CIN8 + (gidx * 16) * 8 + g) * PIX;
    float* ob = out + ((size_t)b * CIN8 + (gidx * 16) * 8 + g) * PIX + p;
#pragma unroll 4
    for (int cc = 0; cc < 16; ++cc) {
        float a = 0.f;
#pragma unroll
        for (int t = 0; t < 9; ++t)
            a = fmaf(wr[t], bf2f(xc[off[t]]), a);
        ob[(size_t)cc * 8 * PIX] = a;
        xc += (size_t)8 * PIX;
    }
}

// ---------------------------------------------------------------------------
extern "C" void kernel_launch(void* const* d_in, const int* in_sizes, int n_in,
                              void* d_out, int out_size, void* d_ws, size_t ws_size,
                              hipStream_t stream) {
    (void)in_sizes; (void)n_in; (void)out_size; (void)ws_size;
    const float* x     = (const float*)d_in[0];
    const float* w_v   = (const float*)d_in[1];
    const float* w1    = (const float*)d_in[2];
    const float* gamma = (const float*)d_in[3];
    const float* beta  = (const float*)d_in[4];
    const float* w2    = (const float*)d_in[5];
    const float* b2    = (const float*)d_in[6];
    float* out = (float*)d_out;

    char* ws = (char*)d_ws;
    unsigned short* Wbig = (unsigned short*)ws;                    //    786,432 B
    unsigned short* xbfT = (unsigned short*)(ws + 786432);         // 25,690,112 B  [b][p][k]
    unsigned short* xv   = (unsigned short*)(ws + 26476544);       // 25,690,112 B  [b][ch][p]
    float* y1    = (float*)(ws + 52166656);                        // 25,690,112 B
    float* stats = (float*)(ws + 77856768);                        //      2,048 B
    float* wgt   = (float*)(ws + 77858816);                        // 28,901,376 B

    cvt_t_kernel<<<3136, 256, 0, stream>>>(x, xbfT);
    build_w_kernel<<<1536, 256, 0, stream>>>(w_v, w1, Wbig);
    gemm_kernel<<<1200, 256, 0, stream>>>(xbfT, Wbig, xv, y1);
    gn_stats_kernel<<<256, 256, 0, stream>>>(y1, stats);
    wgt_kernel<<<784, 256, 0, stream>>>(y1, stats, gamma, beta, w2, b2, wgt);
    final_kernel<<<256 * 13, 256, 0, stream>>>(wgt, xv, out);
}

// Round 6
// 236.042 us; speedup vs baseline: 1.5908x; 1.0415x over previous
//
#include <hip/hip_runtime.h>

// Problem constants (b=8, H=W=56, cin=64, cout=64, cmid=32, k=3, G=4, gc=16)
// ALL inputs and the output are float32. Internal GEMM in bf16 (absmax 0.125 vs thr 0.5275).
#define BATCH 8
#define PIX   3136          // 56*56
#define CIN8  512           // cin*8
#define CMID8 256
#define KDIM  512

typedef short short8 __attribute__((ext_vector_type(8)));
typedef float f32x4 __attribute__((ext_vector_type(4)));

__constant__ int c_perms[8][8] = {
    {0, 1, 2, 3, 4, 5, 6, 7},
    {3, 0, 1, 2, 5, 6, 7, 4},
    {2, 3, 0, 1, 6, 7, 4, 5},
    {1, 2, 3, 0, 7, 4, 5, 6},
    {4, 5, 6, 7, 0, 1, 2, 3},
    {5, 6, 7, 4, 3, 0, 1, 2},
    {6, 7, 4, 5, 2, 3, 0, 1},
};
__constant__ int c_perm7[8] = {7, 4, 5, 6, 1, 2, 3, 0};

// TAB[g][p]: source tap (ki'*3+kj') in wgt for output tap p=ki*3+kj  [verified R1]
__constant__ int c_tab[8][9] = {
    {0, 1, 2, 3, 4, 5, 6, 7, 8},
    {2, 5, 8, 1, 4, 7, 0, 3, 6},
    {8, 7, 6, 5, 4, 3, 2, 1, 0},
    {6, 3, 0, 7, 4, 1, 8, 5, 2},
    {2, 1, 0, 5, 4, 3, 8, 7, 6},
    {8, 5, 2, 7, 4, 1, 6, 3, 0},
    {6, 7, 8, 3, 4, 5, 0, 1, 2},
    {0, 3, 6, 1, 4, 7, 2, 5, 8},
};

__device__ __forceinline__ float bf2f(unsigned short u) {
    union { unsigned int i; float f; } v;
    v.i = ((unsigned int)u) << 16;
    return v.f;
}
__device__ __forceinline__ unsigned short f2bf(float f) {
    union { float f; unsigned int u; } v;
    v.f = f;
    unsigned int u = v.u;
    u += 0x7FFFu + ((u >> 16) & 1u);   // RNE
    return (unsigned short)(u >> 16);
}

// async global->LDS, 16B per lane; LDS dest = uniform base + lane*16 [m97/m104]
__device__ __forceinline__ void gload_lds16(const unsigned short* g, unsigned short* l) {
    __builtin_amdgcn_global_load_lds(
        (const __attribute__((address_space(1))) unsigned int*)g,
        (__attribute__((address_space(3))) unsigned int*)l,
        16, 0, 0);
}

// ---------------------------------------------------------------------------
// K0a: fused convert + TRANSPOSE: x[b][k][p] f32 -> xbfT[b][p][k] bf16. (unchanged)
// ---------------------------------------------------------------------------
#define LDT 70
__global__ __launch_bounds__(256) void cvt_t_kernel(
    const float* __restrict__ x, unsigned short* __restrict__ xbfT)
{
    __shared__ unsigned short T[64 * LDT];
    const int flat = blockIdx.x;            // 8 * 49 * 8 = 3136 blocks
    const int kt = flat & 7;
    const int pt = (flat >> 3) % 49;
    const int b  = flat / (49 * 8);
    const int k0 = kt * 64, p0 = pt * 64;

    const float* xb = x + ((size_t)b * CIN8 + k0) * PIX + p0;
    const int kl = threadIdx.x >> 4;        // 0..15
    const int pl = (threadIdx.x & 15) * 4;  // 0..60
#pragma unroll
    for (int pass = 0; pass < 4; ++pass) {
        int kk = kl + pass * 16;
        float4 v = *(const float4*)(xb + (size_t)kk * PIX + pl);
        ushort2 lo = {f2bf(v.x), f2bf(v.y)};
        ushort2 hi = {f2bf(v.z), f2bf(v.w)};
        *(ushort2*)&T[kk * LDT + pl]     = lo;
        *(ushort2*)&T[kk * LDT + pl + 2] = hi;
    }
    __syncthreads();
    const int prow = threadIdx.x >> 2;        // 0..63
    const int kc8  = (threadIdx.x & 3) * 8;   // 0,8,16,24
    unsigned short* ob = xbfT + ((size_t)b * PIX + p0 + prow) * KDIM + k0;
#pragma unroll
    for (int pass = 0; pass < 2; ++pass) {
        int kk = kc8 + pass * 32;
        unsigned short tmp[8];
#pragma unroll
        for (int j = 0; j < 8; ++j) tmp[j] = T[(kk + j) * LDT + prow];
        *(uint4*)(ob + kk) = *(const uint4*)tmp;
    }
}

// ---------------------------------------------------------------------------
// K0b: build 768x512 permuted weight matrix in bf16, k-contiguous. (unchanged)
// ---------------------------------------------------------------------------
__global__ __launch_bounds__(256) void build_w_kernel(
    const float* __restrict__ w_v, const float* __restrict__ w1,
    unsigned short* __restrict__ Wbig)
{
    int idx = blockIdx.x * 256 + threadIdx.x;     // 768*512 = 393216 exact
    int r = idx >> 9;
    int k = idx & 511;
    int i = k >> 3, f = k & 7;
    float v;
    if (r < 512) {
        int o = r >> 3, g = r & 7;
        int pf = (g < 7) ? c_perms[g][f] : c_perm7[f];
        v = w_v[(o * 64 + i) * 8 + pf];
    } else {
        int rr = r - 512;
        int o = rr >> 3, g = rr & 7;
        int pf = (g < 7) ? c_perms[g][f] : c_perm7[f];
        v = w1[(o * 64 + i) * 8 + pf];
    }
    Wbig[idx] = f2bf(v);
}

// ---------------------------------------------------------------------------
// K1 (m97-style): 128x128 tile, BK=32, UNPADDED LDS (32 shorts/row),
// staging via global_load_lds dwordx4 (async, no VGPR round-trip).
// Grid 6 x 200 (200%8==0): XCD = pt%8 -> row-tiles of a pixel tile share L2.
// ---------------------------------------------------------------------------
__global__ __launch_bounds__(256) void gemm_kernel(
    const unsigned short* __restrict__ xT,    // [25088][512]
    const unsigned short* __restrict__ Wbig,  // [768][512]
    unsigned short* __restrict__ xv,          // [8][512][3136] bf16
    float* __restrict__ y1)                   // [8][256][3136] f32
{
    __shared__ unsigned short Wt[128 * 32];   // 8 KB
    __shared__ unsigned short Xt[128 * 32];   // 8 KB

    const int flat = blockIdx.x;        // 6*200 = 1200
    const int rt   = flat / 200;
    const int pt   = flat % 200;
    if (pt >= 196) return;              // whole block exits together
    const int row0 = rt * 128;
    const int P0   = pt * 128;

    const int tid  = threadIdx.x;
    const int lane = tid & 63;
    const int wave = tid >> 6;
    const int wm   = wave & 1;          // M half
    const int wn   = wave >> 1;         // N half

    f32x4 acc[4][4];
#pragma unroll
    for (int i = 0; i < 4; ++i)
#pragma unroll
        for (int j = 0; j < 4; ++j) acc[i][j] = (f32x4){0.f, 0.f, 0.f, 0.f};

    // staging: one wave-inst covers 16 rows x 32 shorts (1 KB);
    // lane l -> row l/4, k-chunk (l&3)*8. Wave handles rows [wave*32, wave*32+32).
    const int lr = lane >> 2;
    const int lk = (lane & 3) * 8;
    const unsigned short* wsrc = Wbig + (size_t)(row0 + wave * 32 + lr) * KDIM + lk;
    const unsigned short* xsrc = xT + (size_t)(P0 + wave * 32 + lr) * KDIM + lk;
    unsigned short* wdst = &Wt[(wave * 32) * 32];
    unsigned short* xdst = &Xt[(wave * 32) * 32];

    const int m16 = lane & 15;
    const int q8  = (lane >> 4) * 8;

    for (int kc = 0; kc < 16; ++kc) {
        const int k0 = kc * 32;
        gload_lds16(wsrc + k0,             wdst);
        gload_lds16(wsrc + 16 * KDIM + k0, wdst + 16 * 32);
        gload_lds16(xsrc + k0,             xdst);
        gload_lds16(xsrc + 16 * KDIM + k0, xdst + 16 * 32);
        __syncthreads();   // compiler emits vmcnt(0) drain before barrier

        short8 bfrag[4];
#pragma unroll
        for (int nt = 0; nt < 4; ++nt)
            bfrag[nt] = *(const short8*)&Xt[(wn * 64 + nt * 16 + m16) * 32 + q8];
#pragma unroll
        for (int mt = 0; mt < 4; ++mt) {
            short8 afrag = *(const short8*)&Wt[(wm * 64 + mt * 16 + m16) * 32 + q8];
#pragma unroll
            for (int nt = 0; nt < 4; ++nt)
                acc[mt][nt] = __builtin_amdgcn_mfma_f32_16x16x32_bf16(
                    afrag, bfrag[nt], acc[mt][nt], 0, 0, 0);
        }
        __syncthreads();
    }

    // epilogue: C/D layout col(n)=lane&15, row(m)=(lane>>4)*4+reg  [m89/m91]
    const int qm = (lane >> 4) * 4;
#pragma unroll
    for (int nt = 0; nt < 4; ++nt) {
        const int col = P0 + wn * 64 + nt * 16 + m16;   // < 25088
        const int bb  = col / PIX;
        const int pp  = col - bb * PIX;
        if (row0 < 512) {
            unsigned short* dst = xv + ((size_t)bb * CIN8) * PIX + pp;
#pragma unroll
            for (int mt = 0; mt < 4; ++mt) {
                const int m = row0 + wm * 64 + mt * 16 + qm;
#pragma unroll
                for (int r = 0; r < 4; ++r)
                    dst[(size_t)(m + r) * PIX] = f2bf(acc[mt][nt][r]);
            }
        } else {
            float* dst = y1 + ((size_t)bb * CMID8) * PIX + pp;
#pragma unroll
            for (int mt = 0; mt < 4; ++mt) {
                const int m = (row0 - 512) + wm * 64 + mt * 16 + qm;
#pragma unroll
                for (int r = 0; r < 4; ++r)
                    dst[(size_t)(m + r) * PIX] = acc[mt][nt][r];
            }
        }
    }
}

// ---------------------------------------------------------------------------
// K2: GroupNorm stats (unchanged).
// ---------------------------------------------------------------------------
__global__ __launch_bounds__(256) void gn_stats_kernel(
    const float* __restrict__ y1, float* __restrict__ stats)
{
    const float* base = y1 + (size_t)blockIdx.x * 25088;
    float s = 0.f, ss = 0.f;
    for (int i = threadIdx.x; i < 25088; i += 256) {
        float v = base[i];
        s += v; ss += v * v;
    }
#pragma unroll
    for (int off = 32; off; off >>= 1) {
        s  += __shfl_down(s, off);
        ss += __shfl_down(ss, off);
    }
    __shared__ float red[8];
    int wave = threadIdx.x >> 6, lane = threadIdx.x & 63;
    if (lane == 0) { red[wave * 2] = s; red[wave * 2 + 1] = ss; }
    __syncthreads();
    if (threadIdx.x == 0) {
        float S  = red[0] + red[2] + red[4] + red[6];
        float SS = red[1] + red[3] + red[5] + red[7];
        float mean = S * (1.f / 25088.f);
        float var  = SS * (1.f / 25088.f) - mean * mean;
        stats[blockIdx.x * 2]     = mean;
        stats[blockIdx.x * 2 + 1] = rsqrtf(var + 1e-5f);
    }
}

// ---------------------------------------------------------------------------
// K3+K4 FUSED: thread = (b,g,gidx,p). Computes the 9 dynamic taps on the fly
// (normalize+ReLU+9x32 matmul from y1) then the 16-cc multiply-sum from xv.
// Eliminates the wgt tensor (29 MB write + 29 MB read) and one launch.
// ---------------------------------------------------------------------------
__global__ __launch_bounds__(256) void final_fused_kernel(
    const float* __restrict__ y1, const float* __restrict__ stats,
    const float* __restrict__ gamma, const float* __restrict__ beta,
    const float* __restrict__ w2, const float* __restrict__ b2,
    const unsigned short* __restrict__ xv,
    float* __restrict__ out)
{
    const int combo = blockIdx.x / 13;           // b*32 + g*4 + gidx
    const int b    = combo >> 5;
    const int g    = (combo >> 2) & 7;
    const int gidx = combo & 3;

    __shared__ float w2s[9 * 32];
    __shared__ float b2s9[9];
    __shared__ float scs[32], shs[32];
    const int tid = threadIdx.x;
    for (int i = tid; i < 288; i += 256) w2s[i] = w2[gidx * 9 * 32 + i];
    if (tid < 9) b2s9[tid] = b2[gidx * 9 + tid];
    if (tid < 32) {
        float mean = stats[(b * 32 + tid) * 2];
        float rstd = stats[(b * 32 + tid) * 2 + 1];
        float sc = rstd * gamma[tid * 8 + g];
        scs[tid] = sc;
        shs[tid] = beta[tid * 8 + g] - mean * sc;
    }
    __syncthreads();

    const int p = (blockIdx.x % 13) * 256 + tid;
    if (p >= PIX) return;
    const int h = p / 56, w = p % 56;

    // normalized+ReLU t[32] at pixel p (coalesced across p)
    float t[32];
    const float* yb = y1 + ((size_t)b * CMID8 + g) * PIX + p;
#pragma unroll
    for (int i = 0; i < 32; ++i) {
        float v = yb[(size_t)(i * 8) * PIX] * scs[i] + shs[i];
        t[i] = v > 0.f ? v : 0.f;
    }

    // 9 taps
    float wt[9];
#pragma unroll
    for (int tt = 0; tt < 9; ++tt) {
        float a = b2s9[tt];
#pragma unroll
        for (int i = 0; i < 32; ++i) a = fmaf(w2s[tt * 32 + i], t[i], a);
        wt[tt] = a;
    }

    // per-window-tap: remapped weight (0 if OOB) + safe offset
    float wr[9];
    int   off[9];
#pragma unroll
    for (int tt = 0; tt < 9; ++tt) {
        int ki = tt / 3, kj = tt % 3;
        int hh = h + ki - 1, ww = w + kj - 1;
        bool valid = (hh >= 0) & (hh < 56) & (ww >= 0) & (ww < 56);
        wr[tt]  = valid ? wt[c_tab[g][tt]] : 0.f;
        off[tt] = valid ? (hh * 56 + ww) : 0;
    }

    const unsigned short* xc = xv + ((size_t)b * CIN8 + (gidx * 16) * 8 + g) * PIX;
    float* ob = out + ((size_t)b * CIN8 + (gidx * 16) * 8 + g) * PIX + p;
#pragma unroll 4
    for (int cc = 0; cc < 16; ++cc) {
        float a = 0.f;
#pragma unroll
        for (int tt = 0; tt < 9; ++tt)
            a = fmaf(wr[tt], bf2f(xc[off[tt]]), a);
        ob[(size_t)cc * 8 * PIX] = a;
        xc += (size_t)8 * PIX;
    }
}

// ---------------------------------------------------------------------------
extern "C" void kernel_launch(void* const* d_in, const int* in_sizes, int n_in,
                              void* d_out, int out_size, void* d_ws, size_t ws_size,
                              hipStream_t stream) {
    (void)in_sizes; (void)n_in; (void)out_size; (void)ws_size;
    const float* x     = (const float*)d_in[0];
    const float* w_v   = (const float*)d_in[1];
    const float* w1    = (const float*)d_in[2];
    const float* gamma = (const float*)d_in[3];
    const float* beta  = (const float*)d_in[4];
    const float* w2    = (const float*)d_in[5];
    const float* b2    = (const float*)d_in[6];
    float* out = (float*)d_out;

    char* ws = (char*)d_ws;
    unsigned short* Wbig = (unsigned short*)ws;                    //    786,432 B
    unsigned short* xbfT = (unsigned short*)(ws + 786432);         // 25,690,112 B  [b][p][k]
    unsigned short* xv   = (unsigned short*)(ws + 26476544);       // 25,690,112 B  [b][ch][p]
    float* y1    = (float*)(ws + 52166656);                        // 25,690,112 B
    float* stats = (float*)(ws + 77856768);                        //      2,048 B

    cvt_t_kernel<<<3136, 256, 0, stream>>>(x, xbfT);
    build_w_kernel<<<1536, 256, 0, stream>>>(w_v, w1, Wbig);
    gemm_kernel<<<1200, 256, 0, stream>>>(xbfT, Wbig, xv, y1);
    gn_stats_kernel<<<256, 256, 0, stream>>>(y1, stats);
    final_fused_kernel<<<256 * 13, 256, 0, stream>>>(
        y1, stats, gamma, beta, w2, b2, xv, out);
}

// Round 7
// 201.785 us; speedup vs baseline: 1.8609x; 1.1698x over previous
//
#include <hip/hip_runtime.h>

// Problem constants (b=8, H=W=56, cin=64, cout=64, cmid=32, k=3, G=4, gc=16)
// ALL inputs and the output are float32. Internal GEMM in bf16 (absmax 0.125 vs thr 0.5275).
#define BATCH 8
#define PIX   3136          // 56*56
#define CIN8  512           // cin*8
#define CMID8 256
#define KDIM  512

typedef short short8 __attribute__((ext_vector_type(8)));
typedef float f32x4 __attribute__((ext_vector_type(4)));

__constant__ int c_perms[8][8] = {
    {0, 1, 2, 3, 4, 5, 6, 7},
    {3, 0, 1, 2, 5, 6, 7, 4},
    {2, 3, 0, 1, 6, 7, 4, 5},
    {1, 2, 3, 0, 7, 4, 5, 6},
    {4, 5, 6, 7, 0, 1, 2, 3},
    {5, 6, 7, 4, 3, 0, 1, 2},
    {6, 7, 4, 5, 2, 3, 0, 1},
};
__constant__ int c_perm7[8] = {7, 4, 5, 6, 1, 2, 3, 0};

// TAB[g][p]: source tap (ki'*3+kj') in wgt for output tap p=ki*3+kj  [verified R1]
__constant__ int c_tab[8][9] = {
    {0, 1, 2, 3, 4, 5, 6, 7, 8},
    {2, 5, 8, 1, 4, 7, 0, 3, 6},
    {8, 7, 6, 5, 4, 3, 2, 1, 0},
    {6, 3, 0, 7, 4, 1, 8, 5, 2},
    {2, 1, 0, 5, 4, 3, 8, 7, 6},
    {8, 5, 2, 7, 4, 1, 6, 3, 0},
    {6, 7, 8, 3, 4, 5, 0, 1, 2},
    {0, 3, 6, 1, 4, 7, 2, 5, 8},
};

__device__ __forceinline__ float bf2f(unsigned short u) {
    union { unsigned int i; float f; } v;
    v.i = ((unsigned int)u) << 16;
    return v.f;
}
__device__ __forceinline__ unsigned short f2bf(float f) {
    union { float f; unsigned int u; } v;
    v.f = f;
    unsigned int u = v.u;
    u += 0x7FFFu + ((u >> 16) & 1u);   // RNE
    return (unsigned short)(u >> 16);
}
__device__ __forceinline__ float bflo(unsigned int u) {
    union { unsigned int i; float f; } v; v.i = u << 16; return v.f;
}
__device__ __forceinline__ float bfhi(unsigned int u) {
    union { unsigned int i; float f; } v; v.i = u & 0xFFFF0000u; return v.f;
}

// async global->LDS, 16B per lane; LDS dest = uniform base + lane*16 [m97/m104]
__device__ __forceinline__ void gload_lds16(const unsigned short* g, unsigned short* l) {
    __builtin_amdgcn_global_load_lds(
        (const __attribute__((address_space(1))) unsigned int*)g,
        (__attribute__((address_space(3))) unsigned int*)l,
        16, 0, 0);
}

// ---------------------------------------------------------------------------
// K0a: fused convert + TRANSPOSE: x[b][k][p] f32 -> xbfT[b][p][k] bf16. (unchanged)
// ---------------------------------------------------------------------------
#define LDT 70
__global__ __launch_bounds__(256) void cvt_t_kernel(
    const float* __restrict__ x, unsigned short* __restrict__ xbfT)
{
    __shared__ unsigned short T[64 * LDT];
    const int flat = blockIdx.x;            // 8 * 49 * 8 = 3136 blocks
    const int kt = flat & 7;
    const int pt = (flat >> 3) % 49;
    const int b  = flat / (49 * 8);
    const int k0 = kt * 64, p0 = pt * 64;

    const float* xb = x + ((size_t)b * CIN8 + k0) * PIX + p0;
    const int kl = threadIdx.x >> 4;        // 0..15
    const int pl = (threadIdx.x & 15) * 4;  // 0..60
#pragma unroll
    for (int pass = 0; pass < 4; ++pass) {
        int kk = kl + pass * 16;
        float4 v = *(const float4*)(xb + (size_t)kk * PIX + pl);
        ushort2 lo = {f2bf(v.x), f2bf(v.y)};
        ushort2 hi = {f2bf(v.z), f2bf(v.w)};
        *(ushort2*)&T[kk * LDT + pl]     = lo;
        *(ushort2*)&T[kk * LDT + pl + 2] = hi;
    }
    __syncthreads();
    const int prow = threadIdx.x >> 2;        // 0..63
    const int kc8  = (threadIdx.x & 3) * 8;   // 0,8,16,24
    unsigned short* ob = xbfT + ((size_t)b * PIX + p0 + prow) * KDIM + k0;
#pragma unroll
    for (int pass = 0; pass < 2; ++pass) {
        int kk = kc8 + pass * 32;
        unsigned short tmp[8];
#pragma unroll
        for (int j = 0; j < 8; ++j) tmp[j] = T[(kk + j) * LDT + prow];
        *(uint4*)(ob + kk) = *(const uint4*)tmp;
    }
}

// ---------------------------------------------------------------------------
// K0b: build 768x512 permuted weight matrix in bf16, k-contiguous. (unchanged)
// ---------------------------------------------------------------------------
__global__ __launch_bounds__(256) void build_w_kernel(
    const float* __restrict__ w_v, const float* __restrict__ w1,
    unsigned short* __restrict__ Wbig)
{
    int idx = blockIdx.x * 256 + threadIdx.x;     // 768*512 = 393216 exact
    int r = idx >> 9;
    int k = idx & 511;
    int i = k >> 3, f = k & 7;
    float v;
    if (r < 512) {
        int o = r >> 3, g = r & 7;
        int pf = (g < 7) ? c_perms[g][f] : c_perm7[f];
        v = w_v[(o * 64 + i) * 8 + pf];
    } else {
        int rr = r - 512;
        int o = rr >> 3, g = rr & 7;
        int pf = (g < 7) ? c_perms[g][f] : c_perm7[f];
        v = w1[(o * 64 + i) * 8 + pf];
    }
    Wbig[idx] = f2bf(v);
}

// ---------------------------------------------------------------------------
// K1 (unchanged from R5): 128x128 tile, BK=32, global_load_lds staging.
// ---------------------------------------------------------------------------
__global__ __launch_bounds__(256) void gemm_kernel(
    const unsigned short* __restrict__ xT,    // [25088][512]
    const unsigned short* __restrict__ Wbig,  // [768][512]
    unsigned short* __restrict__ xv,          // [8][512][3136] bf16
    float* __restrict__ y1)                   // [8][256][3136] f32
{
    __shared__ unsigned short Wt[128 * 32];   // 8 KB
    __shared__ unsigned short Xt[128 * 32];   // 8 KB

    const int flat = blockIdx.x;        // 6*200 = 1200
    const int rt   = flat / 200;
    const int pt   = flat % 200;
    if (pt >= 196) return;              // whole block exits together
    const int row0 = rt * 128;
    const int P0   = pt * 128;

    const int tid  = threadIdx.x;
    const int lane = tid & 63;
    const int wave = tid >> 6;
    const int wm   = wave & 1;          // M half
    const int wn   = wave >> 1;         // N half

    f32x4 acc[4][4];
#pragma unroll
    for (int i = 0; i < 4; ++i)
#pragma unroll
        for (int j = 0; j < 4; ++j) acc[i][j] = (f32x4){0.f, 0.f, 0.f, 0.f};

    const int lr = lane >> 2;
    const int lk = (lane & 3) * 8;
    const unsigned short* wsrc = Wbig + (size_t)(row0 + wave * 32 + lr) * KDIM + lk;
    const unsigned short* xsrc = xT + (size_t)(P0 + wave * 32 + lr) * KDIM + lk;
    unsigned short* wdst = &Wt[(wave * 32) * 32];
    unsigned short* xdst = &Xt[(wave * 32) * 32];

    const int m16 = lane & 15;
    const int q8  = (lane >> 4) * 8;

    for (int kc = 0; kc < 16; ++kc) {
        const int k0 = kc * 32;
        gload_lds16(wsrc + k0,             wdst);
        gload_lds16(wsrc + 16 * KDIM + k0, wdst + 16 * 32);
        gload_lds16(xsrc + k0,             xdst);
        gload_lds16(xsrc + 16 * KDIM + k0, xdst + 16 * 32);
        __syncthreads();

        short8 bfrag[4];
#pragma unroll
        for (int nt = 0; nt < 4; ++nt)
            bfrag[nt] = *(const short8*)&Xt[(wn * 64 + nt * 16 + m16) * 32 + q8];
#pragma unroll
        for (int mt = 0; mt < 4; ++mt) {
            short8 afrag = *(const short8*)&Wt[(wm * 64 + mt * 16 + m16) * 32 + q8];
#pragma unroll
            for (int nt = 0; nt < 4; ++nt)
                acc[mt][nt] = __builtin_amdgcn_mfma_f32_16x16x32_bf16(
                    afrag, bfrag[nt], acc[mt][nt], 0, 0, 0);
        }
        __syncthreads();
    }

    const int qm = (lane >> 4) * 4;
#pragma unroll
    for (int nt = 0; nt < 4; ++nt) {
        const int col = P0 + wn * 64 + nt * 16 + m16;   // < 25088
        const int bb  = col / PIX;
        const int pp  = col - bb * PIX;
        if (row0 < 512) {
            unsigned short* dst = xv + ((size_t)bb * CIN8) * PIX + pp;
#pragma unroll
            for (int mt = 0; mt < 4; ++mt) {
                const int m = row0 + wm * 64 + mt * 16 + qm;
#pragma unroll
                for (int r = 0; r < 4; ++r)
                    dst[(size_t)(m + r) * PIX] = f2bf(acc[mt][nt][r]);
            }
        } else {
            float* dst = y1 + ((size_t)bb * CMID8) * PIX + pp;
#pragma unroll
            for (int mt = 0; mt < 4; ++mt) {
                const int m = (row0 - 512) + wm * 64 + mt * 16 + qm;
#pragma unroll
                for (int r = 0; r < 4; ++r)
                    dst[(size_t)(m + r) * PIX] = acc[mt][nt][r];
            }
        }
    }
}

// ---------------------------------------------------------------------------
// K2: GroupNorm stats (unchanged).
// ---------------------------------------------------------------------------
__global__ __launch_bounds__(256) void gn_stats_kernel(
    const float* __restrict__ y1, float* __restrict__ stats)
{
    const float* base = y1 + (size_t)blockIdx.x * 25088;
    float s = 0.f, ss = 0.f;
    for (int i = threadIdx.x; i < 25088; i += 256) {
        float v = base[i];
        s += v; ss += v * v;
    }
#pragma unroll
    for (int off = 32; off; off >>= 1) {
        s  += __shfl_down(s, off);
        ss += __shfl_down(ss, off);
    }
    __shared__ float red[8];
    int wave = threadIdx.x >> 6, lane = threadIdx.x & 63;
    if (lane == 0) { red[wave * 2] = s; red[wave * 2 + 1] = ss; }
    __syncthreads();
    if (threadIdx.x == 0) {
        float S  = red[0] + red[2] + red[4] + red[6];
        float SS = red[1] + red[3] + red[5] + red[7];
        float mean = S * (1.f / 25088.f);
        float var  = SS * (1.f / 25088.f) - mean * mean;
        stats[blockIdx.x * 2]     = mean;
        stats[blockIdx.x * 2 + 1] = rsqrtf(var + 1e-5f);
    }
}

// ---------------------------------------------------------------------------
// K3+K4 FUSED (REWRITTEN): thread = quad of 4 pixels for one (b,g,gidx).
// - w2/b2 staged PRE-PERMUTED by c_tab[g] (block-uniform) -> no reg indexing.
// - taps wt[4][9] streamed from y1 float4 loads.
// - xv: 4 aligned uint loads per (cc,row) cover all 12 window taps of the quad.
// - OOB: weights zeroed; addresses clamped (<=2B overread lands in next ws region).
// grid: 256 combos x 4 blocks; quad index pp < 784.
// ---------------------------------------------------------------------------
__global__ __launch_bounds__(256) void final_fused_kernel(
    const float* __restrict__ y1, const float* __restrict__ stats,
    const float* __restrict__ gamma, const float* __restrict__ beta,
    const float* __restrict__ w2, const float* __restrict__ b2,
    const unsigned short* __restrict__ xv,
    float* __restrict__ out)
{
    const int combo = blockIdx.x >> 2;           // b*32 + g*4 + gidx
    const int b    = combo >> 5;
    const int g    = (combo >> 2) & 7;
    const int gidx = combo & 3;

    __shared__ float w2s[9 * 32];   // permuted: w2s[tt*32+i] = w2[gidx,c_tab[g][tt],i]
    __shared__ float b2s9[9];
    __shared__ float scs[32], shs[32];
    const int tid = threadIdx.x;
    for (int i = tid; i < 288; i += 256) {
        int tt = i >> 5, ic = i & 31;
        w2s[i] = w2[(gidx * 9 + c_tab[g][tt]) * 32 + ic];
    }
    if (tid < 9) b2s9[tid] = b2[gidx * 9 + c_tab[g][tid]];
    if (tid < 32) {
        float mean = stats[(b * 32 + tid) * 2];
        float rstd = stats[(b * 32 + tid) * 2 + 1];
        float sc = rstd * gamma[tid * 8 + g];
        scs[tid] = sc;
        shs[tid] = beta[tid * 8 + g] - mean * sc;
    }
    __syncthreads();

    const int pp = (blockIdx.x & 3) * 256 + tid;  // quad index
    if (pp >= 784) return;
    const int p0 = pp * 4;
    const int h  = p0 / 56;
    const int w0 = p0 % 56;                       // even, 0..52

    // ---- taps wt[px][tt] (already output-tap-permuted via w2s) ----
    float wt[4][9];
#pragma unroll
    for (int i = 0; i < 4; ++i)
#pragma unroll
        for (int tt = 0; tt < 9; ++tt) wt[i][tt] = b2s9[tt];

    const float* yb = y1 + ((size_t)b * CMID8 + g) * PIX + p0;
#pragma unroll 4
    for (int ic = 0; ic < 32; ++ic) {
        float4 v = *(const float4*)(yb + (size_t)(ic * 8) * PIX);
        float t0 = v.x * scs[ic] + shs[ic]; t0 = t0 > 0.f ? t0 : 0.f;
        float t1 = v.y * scs[ic] + shs[ic]; t1 = t1 > 0.f ? t1 : 0.f;
        float t2 = v.z * scs[ic] + shs[ic]; t2 = t2 > 0.f ? t2 : 0.f;
        float t3 = v.w * scs[ic] + shs[ic]; t3 = t3 > 0.f ? t3 : 0.f;
#pragma unroll
        for (int tt = 0; tt < 9; ++tt) {
            float wv = w2s[tt * 32 + ic];
            wt[0][tt] = fmaf(wv, t0, wt[0][tt]);
            wt[1][tt] = fmaf(wv, t1, wt[1][tt]);
            wt[2][tt] = fmaf(wv, t2, wt[2][tt]);
            wt[3][tt] = fmaf(wv, t3, wt[3][tt]);
        }
    }

    // ---- OOB zeroing + clamped row bases ----
    int rb[3];
#pragma unroll
    for (int ki = 0; ki < 3; ++ki) {
        int hh = h + ki - 1;
        bool rv = (hh >= 0) & (hh < 56);
        int hc = hh < 0 ? 0 : (hh > 55 ? 55 : hh);
        rb[ki] = hc * 56;
        if (!rv) {
#pragma unroll
            for (int i = 0; i < 4; ++i)
#pragma unroll
                for (int kj = 0; kj < 3; ++kj) wt[i][ki * 3 + kj] = 0.f;
        }
    }
#pragma unroll
    for (int i = 0; i < 4; ++i)
#pragma unroll
        for (int tt = 0; tt < 9; ++tt) {
            int ww = w0 + i + (tt % 3) - 1;
            if (ww < 0 || ww >= 56) wt[i][tt] = 0.f;
        }

    const int c0 = (w0 == 0) ? 0 : (w0 - 2);

    // ---- cc loop ----
    const unsigned short* xc = xv + ((size_t)b * CIN8 + gidx * 128 + g) * PIX;
    float* ob = out + ((size_t)b * CIN8 + gidx * 128 + g) * PIX + p0;
#pragma unroll 2
    for (int cc = 0; cc < 16; ++cc) {
        f32x4 a = (f32x4){0.f, 0.f, 0.f, 0.f};
#pragma unroll
        for (int ki = 0; ki < 3; ++ki) {
            const unsigned short* row = xc + rb[ki];
            unsigned int u0 = *(const unsigned int*)(row + c0);
            unsigned int u1 = *(const unsigned int*)(row + w0);
            unsigned int u2 = *(const unsigned int*)(row + w0 + 2);
            unsigned int u3 = *(const unsigned int*)(row + w0 + 4);
            // f[j] = value at ww = w0-2+j ; j=1..6
            float f1 = bfhi(u0);
            float f2 = bflo(u1), f3 = bfhi(u1);
            float f4 = bflo(u2), f5 = bfhi(u2);
            float f6 = bflo(u3);
            const int t0i = ki * 3;
            // px i, kj -> f[i+kj+1]
            a[0] = fmaf(wt[0][t0i + 0], f1, a[0]);
            a[0] = fmaf(wt[0][t0i + 1], f2, a[0]);
            a[0] = fmaf(wt[0][t0i + 2], f3, a[0]);
            a[1] = fmaf(wt[1][t0i + 0], f2, a[1]);
            a[1] = fmaf(wt[1][t0i + 1], f3, a[1]);
            a[1] = fmaf(wt[1][t0i + 2], f4, a[1]);
            a[2] = fmaf(wt[2][t0i + 0], f3, a[2]);
            a[2] = fmaf(wt[2][t0i + 1], f4, a[2]);
            a[2] = fmaf(wt[2][t0i + 2], f5, a[2]);
            a[3] = fmaf(wt[3][t0i + 0], f4, a[3]);
            a[3] = fmaf(wt[3][t0i + 1], f5, a[3]);
            a[3] = fmaf(wt[3][t0i + 2], f6, a[3]);
        }
        *(f32x4*)(ob + (size_t)cc * 8 * PIX) = a;
        xc += (size_t)8 * PIX;
    }
}

// ---------------------------------------------------------------------------
extern "C" void kernel_launch(void* const* d_in, const int* in_sizes, int n_in,
                              void* d_out, int out_size, void* d_ws, size_t ws_size,
                              hipStream_t stream) {
    (void)in_sizes; (void)n_in; (void)out_size; (void)ws_size;
    const float* x     = (const float*)d_in[0];
    const float* w_v   = (const float*)d_in[1];
    const float* w1    = (const float*)d_in[2];
    const float* gamma = (const float*)d_in[3];
    const float* beta  = (const float*)d_in[4];
    const float* w2    = (const float*)d_in[5];
    const float* b2    = (const float*)d_in[6];
    float* out = (float*)d_out;

    char* ws = (char*)d_ws;
    unsigned short* Wbig = (unsigned short*)ws;                    //    786,432 B
    unsigned short* xbfT = (unsigned short*)(ws + 786432);         // 25,690,112 B  [b][p][k]
    unsigned short* xv   = (unsigned short*)(ws + 26476544);       // 25,690,112 B  [b][ch][p]
    float* y1    = (float*)(ws + 52166656);                        // 25,690,112 B
    float* stats = (float*)(ws + 77856768);                        //      2,048 B

    cvt_t_kernel<<<3136, 256, 0, stream>>>(x, xbfT);
    build_w_kernel<<<1536, 256, 0, stream>>>(w_v, w1, Wbig);
    gemm_kernel<<<1200, 256, 0, stream>>>(xbfT, Wbig, xv, y1);
    gn_stats_kernel<<<256, 256, 0, stream>>>(y1, stats);
    final_fused_kernel<<<256 * 4, 256, 0, stream>>>(
        y1, stats, gamma, beta, w2, b2, xv, out);
}